// Round 3
// baseline (487.060 us; speedup 1.0000x reference)
//
#include <hip/hip_runtime.h>
#include <hip/hip_bf16.h>
#include <cstdint>

// Problem constants (b=2, s=4096, dim=1024, heads=64, dim_head=64)
#define M_TOK 8192
#define DIM   1024
#define INNER 4096
#define HEADS 64
#define DH    64
#define QSCALE 0.125f      // 64^-0.5
#define EPS    1e-6f

typedef __hip_bfloat16 bf16;
typedef __bf16 bf16x8_t __attribute__((ext_vector_type(8)));
typedef float f32x4_t __attribute__((ext_vector_type(4)));

__device__ __forceinline__ float bfbits2f(unsigned short u) {
  return __uint_as_float(((unsigned)u) << 16);
}
__device__ __forceinline__ unsigned short f2bfbits(float f) {
  __hip_bfloat16 h = __float2bfloat16(f);
  unsigned short u;
  __builtin_memcpy(&u, &h, 2);
  return u;
}

// async global->LDS, 16B per lane. LDS dst must be wave-uniform base + lane*16.
__device__ __forceinline__ void load_lds16(const void* g, void* l) {
  __builtin_amdgcn_global_load_lds(
      (__attribute__((address_space(1))) void*)g,
      (__attribute__((address_space(3))) void*)l, 16, 0, 0);
}

// Raw asm barrier: OPAQUE to the compiler's waitcnt-insertion pass, so no
// implicit vmcnt/lgkmcnt drain is attached (R2 theory: the s_barrier BUILTIN
// gets a vmcnt(0) drain inserted when global_load_lds ops are outstanding,
// which nullified the counted-vmcnt pipeline => 8 full drains per K-tile).
// "memory" clobber still pins compiler-visible LDS/global ops to the correct
// side of the barrier.
__device__ __forceinline__ void asm_barrier() {
  asm volatile("s_barrier" ::: "memory");
}

// XCD-aware block swizzle: XCD x owns M-tiles [x*gy/8, (x+1)*gy/8), N-major
// within the XCD. (R3: cut gemm_out FETCH_SIZE 270->66 MB.)
__device__ __forceinline__ void swizzle_xy(int& bx, int& by) {
  const int gx = gridDim.x, gy = gridDim.y;
  const int id  = blockIdx.x + gx * blockIdx.y;
  const int per = gy >> 3;          // M-tiles per XCD (gy % 8 == 0)
  const int xcd = id & 7;
  const int s   = id >> 3;
  by = xcd * per + (s % per);
  bx = s / per;
}

// ---------------------------------------------------------------------------
// cast x (fp32) -> bf16, same layout. One float4 per thread.
// ---------------------------------------------------------------------------
__global__ __launch_bounds__(256) void castx_kernel(
    const float* __restrict__ x, unsigned short* __restrict__ xb, int n4)
{
  const int i = blockIdx.x * 256 + threadIdx.x;
  if (i < n4) {
    const float4 v = reinterpret_cast<const float4*>(x)[i];
    ushort4 o;
    o.x = f2bfbits(v.x); o.y = f2bfbits(v.y);
    o.z = f2bfbits(v.z); o.w = f2bfbits(v.w);
    reinterpret_cast<ushort4*>(xb)[i] = o;
  }
}

// ---------------------------------------------------------------------------
// transpose-cast: W [R][C] fp32 -> Wt [C][R] bf16.  32x32 LDS tiles.
// ---------------------------------------------------------------------------
__global__ __launch_bounds__(256) void tcast_kernel(
    const float* __restrict__ W, unsigned short* __restrict__ Wt, int R, int C)
{
  __shared__ float tile[32][33];
  const int bx = blockIdx.x * 32;   // C offset
  const int by = blockIdx.y * 32;   // R offset
  const int tx = threadIdx.x & 31;
  const int ty = threadIdx.x >> 5;  // 0..7
#pragma unroll
  for (int k = 0; k < 4; ++k)
    tile[ty + k * 8][tx] = W[(size_t)(by + ty + k * 8) * C + bx + tx];
  __syncthreads();
#pragma unroll
  for (int k = 0; k < 4; ++k)
    Wt[(size_t)(bx + ty + k * 8) * R + by + tx] = f2bfbits(tile[tx][ty + k * 8]);
}

// Dual version: z=0 -> W0 into Wt[0:C*R), z=1 -> W1 into Wt[C*R:2*C*R).
__global__ __launch_bounds__(256) void tcast_dual_kernel(
    const float* __restrict__ W0, const float* __restrict__ W1,
    unsigned short* __restrict__ Wt, int R, int C)
{
  __shared__ float tile[32][33];
  const float* W = blockIdx.z ? W1 : W0;
  unsigned short* dst = Wt + (size_t)blockIdx.z * R * C;
  const int bx = blockIdx.x * 32;
  const int by = blockIdx.y * 32;
  const int tx = threadIdx.x & 31;
  const int ty = threadIdx.x >> 5;
#pragma unroll
  for (int k = 0; k < 4; ++k)
    tile[ty + k * 8][tx] = W[(size_t)(by + ty + k * 8) * C + bx + tx];
  __syncthreads();
#pragma unroll
  for (int k = 0; k < 4; ++k)
    dst[(size_t)(bx + ty + k * 8) * R + by + tx] = f2bfbits(tile[tx][ty + k * 8]);
}

// ---------------------------------------------------------------------------
// 256x256 8-phase GEMM (T2+T3+T4+T5). 512 thr = 8 waves (2M x 4N), BK=64.
// LDS 128 KB: As[2][256x64] + Bs[2][256x64] (double-buffered).
// LDS swizzle: row = 8 x 16B chunks, stored slot = chunk ^ (row&7)
//   (proven conflict-free: SQ_LDS_BANK_CONFLICT == 0 in R1/R2 counters).
//
// R3 change: asm s_barrier everywhere in this kernel (no implicit drains).
// Correctness invariants (m201-verified pattern):
//  - half-tile = 128 rows of one matrix = 2 global_load_lds / thread.
//  - tile T's A staged at T-2 ph2/ph3 into As[T&1]; B staged at T-1 ph0/ph1
//    into Bs[T&1].
//  - staging->read: vmcnt(4) at end of tile T retires all of tile T+1's
//    staging (LDS-DMA writes complete when vmcnt retires).
//  - read->overwrite (WAR): barrier after ph1 separates all waves' A-reads
//    of tile T from T+2.A staging issued in ph2/ph3; in-flight ds_reads
//    complete long before staged data returns from L2/HBM (land-latency
//    argument, same as the verified template which also does not drain
//    lgkm before barriers).
//  - at tile T ph3 end: outstanding loads oldest-first: T+1.B(4), T+2.A(4).
//    vmcnt(4) => tile T+1 fully resident, T+2.A still in flight.  Never 0
//    in steady state (T4).  Tail (T >= NT-2): vmcnt(0).
// MODE: 0 identity, 1 relu, 2 relu*QSCALE.  DUAL: split-N K/V epilogue.
// ---------------------------------------------------------------------------
__device__ __forceinline__ void stage_half(
    const unsigned short* __restrict__ G, unsigned short* L,
    int rowbase, int k0, int K, int h, int tid)
{
#pragma unroll
  for (int j = 0; j < 2; ++j) {
    const int q  = h * 1024 + j * 512 + tid;     // chunk index in 256x64 tile
    const int r  = q >> 3;                       // row 0..255
    const int cg = (tid & 7) ^ (r & 7);          // global k-chunk (inverse swz)
    load_lds16(&G[(size_t)(rowbase + r) * K + k0 + cg * 8], &L[q * 8]);
  }
}

template <int MODE, int DUAL>
__global__ __launch_bounds__(512, 2) void gemm256(
    const unsigned short* __restrict__ A,   // [M][K] bf16
    const unsigned short* __restrict__ Bt,  // [N][K] bf16 (B transposed)
    unsigned short* __restrict__ C0,
    unsigned short* __restrict__ C1,
    int N, int K)
{
  __shared__ __align__(16) unsigned short As[2][256 * 64];  // 64 KB
  __shared__ __align__(16) unsigned short Bs[2][256 * 64];  // 64 KB

  int bxi, byi;
  swizzle_xy(bxi, byi);
  const int tid  = threadIdx.x;
  const int bm   = byi * 256;
  const int bn   = bxi * 256;
  const int lane = tid & 63;
  const int w    = tid >> 6;
  const int wm   = (w >> 2) * 128;   // wave M offset (0/128)
  const int wn   = (w & 3) * 64;     // wave N offset (0/64/128/192)
  const int quad = lane >> 4;
  const int l15  = lane & 15;

  f32x4_t acc[8][4];
#pragma unroll
  for (int mt = 0; mt < 8; ++mt)
#pragma unroll
    for (int nt = 0; nt < 4; ++nt) acc[mt][nt] = (f32x4_t){0.f, 0.f, 0.f, 0.f};

  const int NT = K >> 6;

  // ---- prologue: tile0 A+B, tile1 A. vmcnt(4) -> tile0 resident. ----
  stage_half(A,  As[0], bm, 0,  K, 0, tid);
  stage_half(A,  As[0], bm, 0,  K, 1, tid);
  stage_half(Bt, Bs[0], bn, 0,  K, 0, tid);
  stage_half(Bt, Bs[0], bn, 0,  K, 1, tid);
  stage_half(A,  As[1], bm, 64, K, 0, tid);
  stage_half(A,  As[1], bm, 64, K, 1, tid);
  asm volatile("s_waitcnt vmcnt(4)" ::: "memory");
  asm_barrier();

  bf16x8_t af[8][2], bfr[4][2];

  for (int T = 0; T < NT; ++T) {
    const int c = T & 1;
    const unsigned short* Ac = As[c];
    const unsigned short* Bc = Bs[c];
    unsigned short* Bnx = Bs[c ^ 1];   // tile T+1 B lands here
    unsigned short* Anx = As[c];       // tile T+2 A lands here (A reads done ph1)
    const int kB = (T + 1) * 64;
    const int kA = (T + 2) * 64;
    const bool pB = (T + 1 < NT);
    const bool pA = (T + 2 < NT);

    // ===== phase 0: read A m0-3 + B n0-1 (12 b128); stage T+1 B.h0; Q(m0-3,n0-1)
#pragma unroll
    for (int mt = 0; mt < 4; ++mt) {
      const int r = wm + mt * 16 + l15;
#pragma unroll
      for (int kt = 0; kt < 2; ++kt) {
        const int s = (kt * 4 + quad) ^ (r & 7);
        af[mt][kt] = *reinterpret_cast<const bf16x8_t*>(&Ac[r * 64 + s * 8]);
      }
    }
#pragma unroll
    for (int nt = 0; nt < 2; ++nt) {
      const int r = wn + nt * 16 + l15;
#pragma unroll
      for (int kt = 0; kt < 2; ++kt) {
        const int s = (kt * 4 + quad) ^ (r & 7);
        bfr[nt][kt] = *reinterpret_cast<const bf16x8_t*>(&Bc[r * 64 + s * 8]);
      }
    }
    if (pB) stage_half(Bt, Bnx, bn, kB, K, 0, tid);
    asm_barrier();
    __builtin_amdgcn_s_setprio(1);
#pragma unroll
    for (int mt = 0; mt < 4; ++mt)
#pragma unroll
      for (int nt = 0; nt < 2; ++nt) {
        acc[mt][nt] = __builtin_amdgcn_mfma_f32_16x16x32_bf16(
            af[mt][0], bfr[nt][0], acc[mt][nt], 0, 0, 0);
        acc[mt][nt] = __builtin_amdgcn_mfma_f32_16x16x32_bf16(
            af[mt][1], bfr[nt][1], acc[mt][nt], 0, 0, 0);
      }
    __builtin_amdgcn_s_setprio(0);
    asm_barrier();

    // ===== phase 1: read A m4-7 (8 b128); stage T+1 B.h1; Q(m4-7,n0-1)
#pragma unroll
    for (int mt = 4; mt < 8; ++mt) {
      const int r = wm + mt * 16 + l15;
#pragma unroll
      for (int kt = 0; kt < 2; ++kt) {
        const int s = (kt * 4 + quad) ^ (r & 7);
        af[mt][kt] = *reinterpret_cast<const bf16x8_t*>(&Ac[r * 64 + s * 8]);
      }
    }
    if (pB) stage_half(Bt, Bnx, bn, kB, K, 1, tid);
    asm_barrier();
    __builtin_amdgcn_s_setprio(1);
#pragma unroll
    for (int mt = 4; mt < 8; ++mt)
#pragma unroll
      for (int nt = 0; nt < 2; ++nt) {
        acc[mt][nt] = __builtin_amdgcn_mfma_f32_16x16x32_bf16(
            af[mt][0], bfr[nt][0], acc[mt][nt], 0, 0, 0);
        acc[mt][nt] = __builtin_amdgcn_mfma_f32_16x16x32_bf16(
            af[mt][1], bfr[nt][1], acc[mt][nt], 0, 0, 0);
      }
    __builtin_amdgcn_s_setprio(0);
    asm_barrier();

    // ===== phase 2: read B n2-3 (4 b128); stage T+2 A.h0; Q(m0-3,n2-3)
#pragma unroll
    for (int nt = 2; nt < 4; ++nt) {
      const int r = wn + nt * 16 + l15;
#pragma unroll
      for (int kt = 0; kt < 2; ++kt) {
        const int s = (kt * 4 + quad) ^ (r & 7);
        bfr[nt][kt] = *reinterpret_cast<const bf16x8_t*>(&Bc[r * 64 + s * 8]);
      }
    }
    if (pA) stage_half(A, Anx, bm, kA, K, 0, tid);
    asm_barrier();
    __builtin_amdgcn_s_setprio(1);
#pragma unroll
    for (int mt = 0; mt < 4; ++mt)
#pragma unroll
      for (int nt = 2; nt < 4; ++nt) {
        acc[mt][nt] = __builtin_amdgcn_mfma_f32_16x16x32_bf16(
            af[mt][0], bfr[nt][0], acc[mt][nt], 0, 0, 0);
        acc[mt][nt] = __builtin_amdgcn_mfma_f32_16x16x32_bf16(
            af[mt][1], bfr[nt][1], acc[mt][nt], 0, 0, 0);
      }
    __builtin_amdgcn_s_setprio(0);
    asm_barrier();

    // ===== phase 3: stage T+2 A.h1; Q(m4-7,n2-3); counted vmcnt; barrier
    if (pA) stage_half(A, Anx, bm, kA, K, 1, tid);
    asm_barrier();
    __builtin_amdgcn_s_setprio(1);
#pragma unroll
    for (int mt = 4; mt < 8; ++mt)
#pragma unroll
      for (int nt = 2; nt < 4; ++nt) {
        acc[mt][nt] = __builtin_amdgcn_mfma_f32_16x16x32_bf16(
            af[mt][0], bfr[nt][0], acc[mt][nt], 0, 0, 0);
        acc[mt][nt] = __builtin_amdgcn_mfma_f32_16x16x32_bf16(
            af[mt][1], bfr[nt][1], acc[mt][nt], 0, 0, 0);
      }
    __builtin_amdgcn_s_setprio(0);
    if (T < NT - 2) {
      asm volatile("s_waitcnt vmcnt(4)" ::: "memory");  // T+1 resident; T+2.A in flight
    } else {
      asm volatile("s_waitcnt vmcnt(0)" ::: "memory");  // tail drain
    }
    asm_barrier();
  }

  // ---- epilogue ----
  if (DUAL) {
    const bool isK = (bn < 4096);
    unsigned short* __restrict__ C = isK ? C0 : C1;
    const int bnc = bn & 4095;
#pragma unroll
    for (int mt = 0; mt < 8; ++mt)
#pragma unroll
      for (int i = 0; i < 4; ++i) {
        const size_t rowg = (size_t)(bm + wm + mt * 16 + quad * 4 + i);
#pragma unroll
        for (int nt = 0; nt < 4; ++nt) {
          float v = acc[mt][nt][i];
          if (isK) v = fmaxf(v, 0.f);
          C[rowg * 4096 + bnc + wn + nt * 16 + l15] = f2bfbits(v);
        }
      }
  } else {
#pragma unroll
    for (int mt = 0; mt < 8; ++mt)
#pragma unroll
      for (int i = 0; i < 4; ++i) {
        const size_t rowg = (size_t)(bm + wm + mt * 16 + quad * 4 + i);
#pragma unroll
        for (int nt = 0; nt < 4; ++nt) {
          float v = acc[mt][nt][i];
          if (MODE >= 1) v = fmaxf(v, 0.f);
          if (MODE == 2) v *= QSCALE;
          C0[rowg * (size_t)N + bn + wn + nt * 16 + l15] = f2bfbits(v);
        }
      }
  }
}

// ---------------------------------------------------------------------------
// Output MFMA GEMM: out[M,N] = A[M,K] @ Bt[N,K]^T + bias[N], fp32 out.
// 128(M) x 64(N) tile, BK=64 (R4-validated).  Kept on the drain-per-K-step
// structure this round (single-buffered LDS RELIES on the __syncthreads
// drain for staging completion).
// ---------------------------------------------------------------------------
__global__ __launch_bounds__(256) void gemm_out_bf16(
    const unsigned short* __restrict__ A,   // [M][K] bf16
    const unsigned short* __restrict__ Bt,  // [N][K] bf16
    const float* __restrict__ bias,
    float* __restrict__ out, int M, int N, int K)
{
  __shared__ __align__(16) unsigned short As[128 * 64];  // 16 KB
  __shared__ __align__(16) unsigned short Bs[64 * 64];   //  8 KB

  int bxi, byi;
  swizzle_xy(bxi, byi);
  const int tid  = threadIdx.x;
  const int bm   = byi * 128;
  const int bn   = bxi * 64;
  const int lane = tid & 63;
  const int w    = tid >> 6;
  const int wm   = (w & 1) * 64;
  const int wn   = (w >> 1) * 32;
  const int quad = lane >> 4;
  const int l15  = lane & 15;

  f32x4_t acc[4][2];
#pragma unroll
  for (int mt = 0; mt < 4; ++mt)
#pragma unroll
    for (int nt = 0; nt < 2; ++nt) acc[mt][nt] = (f32x4_t){0.f, 0.f, 0.f, 0.f};

  int qa[4], ra[4], ca[4];
#pragma unroll
  for (int j = 0; j < 4; ++j) {
    qa[j] = tid + 256 * j;
    ra[j] = qa[j] >> 3;
    ca[j] = (qa[j] & 7) ^ (ra[j] & 7);
  }
  int qb[2], rb[2], cb[2];
#pragma unroll
  for (int j = 0; j < 2; ++j) {
    qb[j] = tid + 256 * j;
    rb[j] = qb[j] >> 3;
    cb[j] = (qb[j] & 7) ^ (rb[j] & 7);
  }

  for (int k0 = 0; k0 < K; k0 += 64) {
    __syncthreads();
#pragma unroll
    for (int j = 0; j < 4; ++j)
      load_lds16(&A[(size_t)(bm + ra[j]) * K + k0 + ca[j] * 8], &As[qa[j] * 8]);
#pragma unroll
    for (int j = 0; j < 2; ++j)
      load_lds16(&Bt[(size_t)(bn + rb[j]) * K + k0 + cb[j] * 8], &Bs[qb[j] * 8]);
    __syncthreads();

    bf16x8_t af[4][2], bfr[2][2];
#pragma unroll
    for (int mt = 0; mt < 4; ++mt) {
      const int r = wm + mt * 16 + l15;
#pragma unroll
      for (int kt = 0; kt < 2; ++kt) {
        const int slot = (kt * 4 + quad) ^ (r & 7);
        af[mt][kt] = *reinterpret_cast<const bf16x8_t*>(&As[r * 64 + slot * 8]);
      }
    }
#pragma unroll
    for (int nt = 0; nt < 2; ++nt) {
      const int r = wn + nt * 16 + l15;
#pragma unroll
      for (int kt = 0; kt < 2; ++kt) {
        const int slot = (kt * 4 + quad) ^ (r & 7);
        bfr[nt][kt] = *reinterpret_cast<const bf16x8_t*>(&Bs[r * 64 + slot * 8]);
      }
    }
#pragma unroll
    for (int mt = 0; mt < 4; ++mt)
#pragma unroll
      for (int nt = 0; nt < 2; ++nt) {
        acc[mt][nt] = __builtin_amdgcn_mfma_f32_16x16x32_bf16(
            af[mt][0], bfr[nt][0], acc[mt][nt], 0, 0, 0);
        acc[mt][nt] = __builtin_amdgcn_mfma_f32_16x16x32_bf16(
            af[mt][1], bfr[nt][1], acc[mt][nt], 0, 0, 0);
      }
  }

#pragma unroll
  for (int mt = 0; mt < 4; ++mt)
#pragma unroll
    for (int i = 0; i < 4; ++i) {
      const size_t rowg = (size_t)(bm + wm + mt * 16 + quad * 4 + i);
#pragma unroll
      for (int nt = 0; nt < 2; ++nt) {
        const int colg = bn + wn + nt * 16 + l15;
        out[rowg * N + colg] = acc[mt][nt][i] + bias[colg];
      }
    }
}

// ---------------------------------------------------------------------------
// ksum[t][d] = sum_i K[t][i*64+d].  One wave per token, 4 tokens/block.
// ---------------------------------------------------------------------------
__global__ __launch_bounds__(256) void ksum_kernel(
    const unsigned short* __restrict__ Kb, float* __restrict__ ks)
{
  const int t = blockIdx.x * 4 + (threadIdx.x >> 6);
  const int j = threadIdx.x & 63;
  const uint4* row = reinterpret_cast<const uint4*>(Kb + (size_t)t * INNER);
  float s[8] = {0.f, 0.f, 0.f, 0.f, 0.f, 0.f, 0.f, 0.f};
#pragma unroll
  for (int m = 0; m < 8; ++m) {
    const uint4 u = row[j + 64 * m];
    s[0] += __uint_as_float((u.x & 0xFFFFu) << 16);
    s[1] += __uint_as_float(u.x & 0xFFFF0000u);
    s[2] += __uint_as_float((u.y & 0xFFFFu) << 16);
    s[3] += __uint_as_float(u.y & 0xFFFF0000u);
    s[4] += __uint_as_float((u.z & 0xFFFFu) << 16);
    s[5] += __uint_as_float(u.z & 0xFFFF0000u);
    s[6] += __uint_as_float((u.w & 0xFFFFu) << 16);
    s[7] += __uint_as_float(u.w & 0xFFFF0000u);
  }
#pragma unroll
  for (int off = 8; off < 64; off <<= 1)
#pragma unroll
    for (int e = 0; e < 8; ++e) s[e] += __shfl_xor(s[e], off, 64);
  if (j < 8) {
    float4* dst = reinterpret_cast<float4*>(ks + t * 64 + j * 8);
    float4 lo, hi;
    lo.x = s[0]; lo.y = s[1]; lo.z = s[2]; lo.w = s[3];
    hi.x = s[4]; hi.y = s[5]; hi.z = s[6]; hi.w = s[7];
    dst[0] = lo; dst[1] = hi;
  }
}

// ---------------------------------------------------------------------------
// MFMA attention: one wave per token, 4 tokens/block, zero LDS (R3-verified).
// ---------------------------------------------------------------------------
__global__ __launch_bounds__(256) void attn_mfma(
    const unsigned short* __restrict__ Qb, const unsigned short* __restrict__ Vb,
    const float* __restrict__ ksum, unsigned short* __restrict__ Ab)
{
  const int t    = blockIdx.x * 4 + (threadIdx.x >> 6);
  const int lane = threadIdx.x & 63;
  const int l15  = lane & 15;
  const int quad = lane >> 4;
  const size_t base = (size_t)t * INNER;

  union VU { bf16x8_t v; unsigned short u[8]; };

  float ksv[2][8];
#pragma unroll
  for (int kt = 0; kt < 2; ++kt) {
    const float4* p = reinterpret_cast<const float4*>(ksum + t * 64 + kt * 32 + quad * 8);
    const float4 a = p[0], b = p[1];
    ksv[kt][0] = a.x; ksv[kt][1] = a.y; ksv[kt][2] = a.z; ksv[kt][3] = a.w;
    ksv[kt][4] = b.x; ksv[kt][5] = b.y; ksv[kt][6] = b.z; ksv[kt][7] = b.w;
  }

  bf16x8_t vs[4][2];
#pragma unroll
  for (int nt = 0; nt < 4; ++nt)
#pragma unroll
    for (int kt = 0; kt < 2; ++kt) {
      VU vr, vo;
      vr.v = *reinterpret_cast<const bf16x8_t*>(
          Vb + base + (size_t)(nt * 16 + l15) * 64 + kt * 32 + quad * 8);
#pragma unroll
      for (int j = 0; j < 8; ++j)
        vo.u[j] = f2bfbits(bfbits2f(vr.u[j]) * ksv[kt][j]);
      vs[nt][kt] = vo.v;
    }

  bf16x8_t qf[4][2];
  float qn[4] = {0.f, 0.f, 0.f, 0.f};
#pragma unroll
  for (int mt = 0; mt < 4; ++mt)
#pragma unroll
    for (int kt = 0; kt < 2; ++kt) {
      VU qr;
      qr.v = *reinterpret_cast<const bf16x8_t*>(
          Qb + base + (size_t)(mt * 16 + l15) * 64 + kt * 32 + quad * 8);
      qf[mt][kt] = qr.v;
#pragma unroll
      for (int j = 0; j < 8; ++j)
        qn[mt] += bfbits2f(qr.u[j]) * ksv[kt][j];
    }
#pragma unroll
  for (int mt = 0; mt < 4; ++mt) {
    qn[mt] += __shfl_xor(qn[mt], 16, 64);
    qn[mt] += __shfl_xor(qn[mt], 32, 64);
  }

  f32x4_t acc[4][4];
#pragma unroll
  for (int mt = 0; mt < 4; ++mt)
#pragma unroll
    for (int nt = 0; nt < 4; ++nt) acc[mt][nt] = (f32x4_t){0.f, 0.f, 0.f, 0.f};

#pragma unroll
  for (int mt = 0; mt < 4; ++mt)
#pragma unroll
    for (int nt = 0; nt < 4; ++nt) {
      acc[mt][nt] = __builtin_amdgcn_mfma_f32_16x16x32_bf16(
          qf[mt][0], vs[nt][0], acc[mt][nt], 0, 0, 0);
      acc[mt][nt] = __builtin_amdgcn_mfma_f32_16x16x32_bf16(
          qf[mt][1], vs[nt][1], acc[mt][nt], 0, 0, 0);
    }

#pragma unroll
  for (int mt = 0; mt < 4; ++mt)
#pragma unroll
    for (int i = 0; i < 4; ++i) {
      const float inv = 1.f / (__shfl(qn[mt], quad * 4 + i, 64) + EPS);
      const size_t roff = base + (size_t)(mt * 16 + quad * 4 + i) * 64;
#pragma unroll
      for (int nt = 0; nt < 4; ++nt)
        Ab[roff + nt * 16 + l15] = f2bfbits(acc[mt][nt][i] * inv);
    }
}

// ---------------------------------------------------------------------------
// Buffers (ws = 130 MB):
//  ws   @0      : K (transient) -> Q -> A (in place)
//  ws   @64MB   : V ; first 8MB reused for Wo^T after attn
//  ws   @128MB  : ksum (fp32 8192x64, 2MB)
//  d_out@0      : Xb (bf16 8192x1024, 16MB)       — dead before gemm_out writes
//  d_out@16MB   : WtKV (bf16 8192x1024, 16MB)     — then WqT (8MB)
// ---------------------------------------------------------------------------
extern "C" void kernel_launch(void* const* d_in, const int* in_sizes, int n_in,
                              void* d_out, int out_size, void* d_ws, size_t ws_size,
                              hipStream_t stream)
{
  const float* x  = (const float*)d_in[0];
  const float* Wq = (const float*)d_in[1];
  const float* Wk = (const float*)d_in[2];
  const float* Wv = (const float*)d_in[3];
  const float* Wo = (const float*)d_in[4];
  const float* bo = (const float*)d_in[5];
  float* out = (float*)d_out;

  uint8_t* ws = (uint8_t*)d_ws;
  const size_t HALF = (size_t)M_TOK * INNER * sizeof(bf16);  // 64 MB
  unsigned short* KQA = (unsigned short*)ws;            // K -> Q -> A
  unsigned short* Vb  = (unsigned short*)(ws + HALF);   // V ; then Wo^T
  float* ks           = (float*)(ws + 2 * HALF);

  unsigned short* Xb   = (unsigned short*)d_out;                           // 16 MB
  unsigned short* WtKV = (unsigned short*)((uint8_t*)d_out + (16u << 20)); // 16 MB
  unsigned short* WqT  = WtKV;   // reused after gemm_kv
  unsigned short* Wot  = Vb;     // Wo^T over dead V (after attn)

  const dim3 blk(256);
  const dim3 blk512(512);

  castx_kernel<<<dim3(M_TOK * DIM / 4 / 256), blk, 0, stream>>>(
      x, Xb, M_TOK * DIM / 4);

  // Wk^T and Wv^T stacked -> WtKV [8192][1024]
  tcast_dual_kernel<<<dim3(INNER / 32, DIM / 32, 2), blk, 0, stream>>>(
      Wk, Wv, WtKV, DIM, INNER);

  // fused K+V projection: 256^2 8-phase, DUAL epilogue (relu->K, id->V)
  gemm256<0, 1><<<dim3(2 * INNER / 256, M_TOK / 256), blk512, 0, stream>>>(
      Xb, WtKV, KQA, Vb, 2 * INNER, DIM);

  ksum_kernel<<<dim3(M_TOK / 4), blk, 0, stream>>>(KQA, ks);

  tcast_kernel<<<dim3(INNER / 32, DIM / 32), blk, 0, stream>>>(
      Wq, WqT, DIM, INNER);

  // Q projection: relu * QSCALE, overwrites dead K
  gemm256<2, 0><<<dim3(INNER / 256, M_TOK / 256), blk512, 0, stream>>>(
      Xb, WqT, KQA, nullptr, INNER, DIM);

  attn_mfma<<<dim3(M_TOK / 4), blk, 0, stream>>>(KQA, Vb, ks, KQA);  // A in place

  tcast_kernel<<<dim3(DIM / 32, INNER / 32), blk, 0, stream>>>(
      Wo, Wot, INNER, DIM);  // over dead V

  gemm_out_bf16<<<dim3(DIM / 64, M_TOK / 128), blk, 0, stream>>>(
      KQA, Wot, bo, out, M_TOK, DIM, INNER);
}

// Round 5
// 465.095 us; speedup vs baseline: 1.0472x; 1.0472x over previous
//
#include <hip/hip_runtime.h>
#include <hip/hip_bf16.h>
#include <cstdint>

// Problem constants (b=2, s=4096, dim=1024, heads=64, dim_head=64)
#define M_TOK 8192
#define DIM   1024
#define INNER 4096
#define HEADS 64
#define DH    64
#define QSCALE 0.125f      // 64^-0.5
#define EPS    1e-6f

typedef __hip_bfloat16 bf16;
typedef __bf16 bf16x8_t __attribute__((ext_vector_type(8)));
typedef float f32x4_t __attribute__((ext_vector_type(4)));

__device__ __forceinline__ float bfbits2f(unsigned short u) {
  return __uint_as_float(((unsigned)u) << 16);
}
__device__ __forceinline__ unsigned short f2bfbits(float f) {
  __hip_bfloat16 h = __float2bfloat16(f);
  unsigned short u;
  __builtin_memcpy(&u, &h, 2);
  return u;
}

// async global->LDS, 16B per lane. LDS dst must be wave-uniform base + lane*16.
__device__ __forceinline__ void load_lds16(const void* g, void* l) {
  __builtin_amdgcn_global_load_lds(
      (__attribute__((address_space(1))) void*)g,
      (__attribute__((address_space(3))) void*)l, 16, 0, 0);
}

__device__ __forceinline__ void asm_barrier() {
  asm volatile("s_barrier" ::: "memory");
}

// Counted lgkm wait + sched_barrier(0).  The SB is REQUIRED (rule #18):
// hipcc hoists register-only MFMAs above inline-asm lgkmcnt despite the
// "memory" clobber; SB(0) is the fence.  Region boundaries only — the
// code between two waits is left free for the scheduler to interleave.
#define LGKM_SB(N) do { \
    asm volatile("s_waitcnt lgkmcnt(" #N ")" ::: "memory"); \
    __builtin_amdgcn_sched_barrier(0); } while (0)

// XCD-aware block swizzle: XCD x owns M-tiles [x*gy/8, (x+1)*gy/8), N-major
// within the XCD.
__device__ __forceinline__ void swizzle_xy(int& bx, int& by) {
  const int gx = gridDim.x, gy = gridDim.y;
  const int id  = blockIdx.x + gx * blockIdx.y;
  const int per = gy >> 3;          // M-tiles per XCD (gy % 8 == 0)
  const int xcd = id & 7;
  const int s   = id >> 3;
  by = xcd * per + (s % per);
  bx = s / per;
}

// ---------------------------------------------------------------------------
// cast x (fp32) -> bf16, same layout. One float4 per thread.
// ---------------------------------------------------------------------------
__global__ __launch_bounds__(256) void castx_kernel(
    const float* __restrict__ x, unsigned short* __restrict__ xb, int n4)
{
  const int i = blockIdx.x * 256 + threadIdx.x;
  if (i < n4) {
    const float4 v = reinterpret_cast<const float4*>(x)[i];
    ushort4 o;
    o.x = f2bfbits(v.x); o.y = f2bfbits(v.y);
    o.z = f2bfbits(v.z); o.w = f2bfbits(v.w);
    reinterpret_cast<ushort4*>(xb)[i] = o;
  }
}

// ---------------------------------------------------------------------------
// transpose-cast: W [R][C] fp32 -> Wt [C][R] bf16.  32x32 LDS tiles.
// ---------------------------------------------------------------------------
__global__ __launch_bounds__(256) void tcast_kernel(
    const float* __restrict__ W, unsigned short* __restrict__ Wt, int R, int C)
{
  __shared__ float tile[32][33];
  const int bx = blockIdx.x * 32;   // C offset
  const int by = blockIdx.y * 32;   // R offset
  const int tx = threadIdx.x & 31;
  const int ty = threadIdx.x >> 5;  // 0..7
#pragma unroll
  for (int k = 0; k < 4; ++k)
    tile[ty + k * 8][tx] = W[(size_t)(by + ty + k * 8) * C + bx + tx];
  __syncthreads();
#pragma unroll
  for (int k = 0; k < 4; ++k)
    Wt[(size_t)(bx + ty + k * 8) * R + by + tx] = f2bfbits(tile[tx][ty + k * 8]);
}

// Dual version: z=0 -> W0 into Wt[0:C*R), z=1 -> W1 into Wt[C*R:2*C*R).
__global__ __launch_bounds__(256) void tcast_dual_kernel(
    const float* __restrict__ W0, const float* __restrict__ W1,
    unsigned short* __restrict__ Wt, int R, int C)
{
  __shared__ float tile[32][33];
  const float* W = blockIdx.z ? W1 : W0;
  unsigned short* dst = Wt + (size_t)blockIdx.z * R * C;
  const int bx = blockIdx.x * 32;
  const int by = blockIdx.y * 32;
  const int tx = threadIdx.x & 31;
  const int ty = threadIdx.x >> 5;
#pragma unroll
  for (int k = 0; k < 4; ++k)
    tile[ty + k * 8][tx] = W[(size_t)(by + ty + k * 8) * C + bx + tx];
  __syncthreads();
#pragma unroll
  for (int k = 0; k < 4; ++k)
    dst[(size_t)(bx + ty + k * 8) * R + by + tx] = f2bfbits(tile[tx][ty + k * 8]);
}

// ---------------------------------------------------------------------------
// 256x256 slip-pipelined GEMM.  512 thr = 8 waves (2M x 4N), BK=64.
// LDS 128 KB: As[2][256x64] + Bs[2][256x64].  Swizzle: slot = chunk^(row&7)
// (conflict-free, SQ_LDS_BANK_CONFLICT == 0 measured R1-R3).
//
// RESTRUCTURE (R4, resubmitted R5 after infra-failed bench): barrier-lockstep
// (8 barriers/K-tile) left the MFMA pipe idle during LDS delivery and vice
// versa (measured 5662 cyc/K-tile vs 2483 MFMA-bound).  New schedule: ONE
// barrier per K-tile (collective stage->read handoff) + counted lgkmcnt so
// each quadrant's MFMA overlaps the next quadrant's ds_read delivery:
//
//   [seam, prev iter] read af0-3,bfr0-1 of T   (12 ds_reads)
//   top:  read af4-7                           (8)
//         LGKM(8)  -> seam reads done          ; MFMA q0 (m0-3 x n0-1)
//         read bfr2-3 (4); stage B.h0(T+1)
//         LGKM(4)  -> af4-7 done               ; MFMA q1 (m4-7 x n0-1)
//         stage B.h1(T+1); stage A.h0(T+2)
//         LGKM(0)  -> bfr2-3 done              ; MFMA q2 (m0-3 x n2-3)
//         stage A.h1(T+2)                      ; MFMA q3 (m4-7 x n2-3)
//         vmcnt(4) [tail: 0]; s_barrier        ; seam reads for T+1
//
// Hazard proofs (keep when editing):
//  - ds-read->DMA-overwrite (WAR) on As[c]: all As[c] reads (seam af0-3 +
//    top af4-7) retire at LGKM(8)/LGKM(4), which precede the A.h0(T+2)
//    stage issue by >=2 MFMA clusters; DMA lands >=200cy after issue.
//    Cross-wave: reads are each wave's FIRST ops after the tile barrier,
//    retire ~500cy post-barrier; any wave's A-stage lands >=900cy post-
//    barrier (2 clusters + 2 waits + flight).
//  - Bs[c^1] (B of T+1) written mid-T; its last reads were tile T-1's,
//    retired at T-1's LGKM(0), pre-barrier.
//  - stage->read: vmcnt(4) at tile end: queue oldest-first = T+1.A(4,
//    issued T-1), T+1.B(4, issued T), T+2.A(4, issued T) = 12; vmcnt(4)
//    => all of T+1 resident, T+2.A in flight (never drains to 0 in steady
//    state).  Barrier makes residency collective before seam reads.
//  - lgkm counts: only ds_reads touch lgkm here (global_load_lds is
//    vmcnt-only); waits use literal 8/4/0 <= 15 (encoding max).
//  - barriers/waits all in wave-uniform control flow (no deadlock).
// MODE: 0 identity, 1 relu, 2 relu*QSCALE.  DUAL: split-N K/V epilogue.
// ---------------------------------------------------------------------------
__device__ __forceinline__ void stage_half(
    const unsigned short* __restrict__ G, unsigned short* L,
    int rowbase, int k0, int K, int h, int tid)
{
#pragma unroll
  for (int j = 0; j < 2; ++j) {
    const int q  = h * 1024 + j * 512 + tid;     // chunk index in 256x64 tile
    const int r  = q >> 3;                       // row 0..255
    const int cg = (tid & 7) ^ (r & 7);          // global k-chunk (inverse swz)
    load_lds16(&G[(size_t)(rowbase + r) * K + k0 + cg * 8], &L[q * 8]);
  }
}

__device__ __forceinline__ void read_af4(
    const unsigned short* __restrict__ Ac, bf16x8_t (&af)[8][2],
    int m0, int wm, int l15, int quad)
{
#pragma unroll
  for (int mt = 0; mt < 4; ++mt) {
    const int r = wm + (m0 + mt) * 16 + l15;
#pragma unroll
    for (int kt = 0; kt < 2; ++kt) {
      const int s = (kt * 4 + quad) ^ (r & 7);
      af[m0 + mt][kt] = *reinterpret_cast<const bf16x8_t*>(&Ac[r * 64 + s * 8]);
    }
  }
}

__device__ __forceinline__ void read_bf2(
    const unsigned short* __restrict__ Bc, bf16x8_t (&bfr)[4][2],
    int n0, int wn, int l15, int quad)
{
#pragma unroll
  for (int nt = 0; nt < 2; ++nt) {
    const int r = wn + (n0 + nt) * 16 + l15;
#pragma unroll
    for (int kt = 0; kt < 2; ++kt) {
      const int s = (kt * 4 + quad) ^ (r & 7);
      bfr[n0 + nt][kt] = *reinterpret_cast<const bf16x8_t*>(&Bc[r * 64 + s * 8]);
    }
  }
}

__device__ __forceinline__ void mfma_quad(
    f32x4_t (&acc)[8][4], const bf16x8_t (&af)[8][2],
    const bf16x8_t (&bfr)[4][2], int m0, int n0)
{
  __builtin_amdgcn_s_setprio(1);
#pragma unroll
  for (int mt = m0; mt < m0 + 4; ++mt)
#pragma unroll
    for (int nt = n0; nt < n0 + 2; ++nt) {
      acc[mt][nt] = __builtin_amdgcn_mfma_f32_16x16x32_bf16(
          af[mt][0], bfr[nt][0], acc[mt][nt], 0, 0, 0);
      acc[mt][nt] = __builtin_amdgcn_mfma_f32_16x16x32_bf16(
          af[mt][1], bfr[nt][1], acc[mt][nt], 0, 0, 0);
    }
  __builtin_amdgcn_s_setprio(0);
}

template <int MODE, int DUAL>
__global__ __launch_bounds__(512, 2) void gemm256(
    const unsigned short* __restrict__ A,   // [M][K] bf16
    const unsigned short* __restrict__ Bt,  // [N][K] bf16 (B transposed)
    unsigned short* __restrict__ C0,
    unsigned short* __restrict__ C1,
    int N, int K)
{
  __shared__ __align__(16) unsigned short As[2][256 * 64];  // 64 KB
  __shared__ __align__(16) unsigned short Bs[2][256 * 64];  // 64 KB

  int bxi, byi;
  swizzle_xy(bxi, byi);
  const int tid  = threadIdx.x;
  const int bm   = byi * 256;
  const int bn   = bxi * 256;
  const int lane = tid & 63;
  const int w    = tid >> 6;
  const int wm   = (w >> 2) * 128;   // wave M offset (0/128)
  const int wn   = (w & 3) * 64;     // wave N offset (0/64/128/192)
  const int quad = lane >> 4;
  const int l15  = lane & 15;

  f32x4_t acc[8][4];
#pragma unroll
  for (int mt = 0; mt < 8; ++mt)
#pragma unroll
    for (int nt = 0; nt < 4; ++nt) acc[mt][nt] = (f32x4_t){0.f, 0.f, 0.f, 0.f};

  const int NT = K >> 6;

  bf16x8_t af[8][2], bfr[4][2];

  // ---- prologue: tile0 A+B, tile1 A staged; tile0 resident; seam reads ----
  stage_half(A,  As[0], bm, 0,  K, 0, tid);
  stage_half(A,  As[0], bm, 0,  K, 1, tid);
  stage_half(Bt, Bs[0], bn, 0,  K, 0, tid);
  stage_half(Bt, Bs[0], bn, 0,  K, 1, tid);
  stage_half(A,  As[1], bm, 64, K, 0, tid);
  stage_half(A,  As[1], bm, 64, K, 1, tid);
  asm volatile("s_waitcnt vmcnt(4)" ::: "memory");  // tile0 resident; tile1.A in flight
  asm_barrier();
  __builtin_amdgcn_sched_barrier(0);
  read_af4(As[0], af, 0, wm, l15, quad);   // seam for T=0: af0-3
  read_bf2(Bs[0], bfr, 0, wn, l15, quad);  //               bfr0-1

  for (int T = 0; T < NT; ++T) {
    const int c = T & 1;
    const unsigned short* Ac = As[c];
    const unsigned short* Bc = Bs[c];
    unsigned short* Bnx = Bs[c ^ 1];   // tile T+1 B lands here
    unsigned short* Anx = As[c];       // tile T+2 A lands here
    const int kB = (T + 1) * 64;
    const int kA = (T + 2) * 64;
    const bool pB = (T + 1 < NT);
    const bool pA = (T + 2 < NT);

    // region 1: issue q1 frags; wait seam; MFMA q0 overlaps af4-7 delivery
    read_af4(Ac, af, 4, wm, l15, quad);                 // 8 ds_reads
    LGKM_SB(8);                                         // seam (12) retired
    mfma_quad(acc, af, bfr, 0, 0);                      // q0: m0-3 x n0-1

    // region 2: issue q2 frags + B-stage; wait af4-7; MFMA q1 overlaps
    read_bf2(Bc, bfr, 2, wn, l15, quad);                // 4 ds_reads
    if (pB) stage_half(Bt, Bnx, bn, kB, K, 0, tid);
    LGKM_SB(4);                                         // af4-7 retired
    mfma_quad(acc, af, bfr, 4, 0);                      // q1: m4-7 x n0-1

    // region 3: stages; wait bfr2-3; MFMA q2
    if (pB) stage_half(Bt, Bnx, bn, kB, K, 1, tid);
    if (pA) stage_half(A, Anx, bm, kA, K, 0, tid);      // all As[c] reads retired
    LGKM_SB(0);                                         // bfr2-3 retired
    mfma_quad(acc, af, bfr, 0, 2);                      // q2: m0-3 x n2-3

    // region 4: last stage; MFMA q3; tile-boundary handoff
    if (pA) stage_half(A, Anx, bm, kA, K, 1, tid);
    mfma_quad(acc, af, bfr, 4, 2);                      // q3: m4-7 x n2-3
    if (T < NT - 2) {
      asm volatile("s_waitcnt vmcnt(4)" ::: "memory");  // T+1 resident; T+2.A in flight
    } else {
      asm volatile("s_waitcnt vmcnt(0)" ::: "memory");  // tail drain
    }
    asm_barrier();
    __builtin_amdgcn_sched_barrier(0);
    if (T + 1 < NT) {                                   // seam reads for T+1
      read_af4(As[c ^ 1], af, 0, wm, l15, quad);        // af0-3 (8)
      read_bf2(Bs[c ^ 1], bfr, 0, wn, l15, quad);       // bfr0-1 (4)
    }
  }

  // ---- epilogue ----
  if (DUAL) {
    const bool isK = (bn < 4096);
    unsigned short* __restrict__ C = isK ? C0 : C1;
    const int bnc = bn & 4095;
#pragma unroll
    for (int mt = 0; mt < 8; ++mt)
#pragma unroll
      for (int i = 0; i < 4; ++i) {
        const size_t rowg = (size_t)(bm + wm + mt * 16 + quad * 4 + i);
#pragma unroll
        for (int nt = 0; nt < 4; ++nt) {
          float v = acc[mt][nt][i];
          if (isK) v = fmaxf(v, 0.f);
          C[rowg * 4096 + bnc + wn + nt * 16 + l15] = f2bfbits(v);
        }
      }
  } else {
#pragma unroll
    for (int mt = 0; mt < 8; ++mt)
#pragma unroll
      for (int i = 0; i < 4; ++i) {
        const size_t rowg = (size_t)(bm + wm + mt * 16 + quad * 4 + i);
#pragma unroll
        for (int nt = 0; nt < 4; ++nt) {
          float v = acc[mt][nt][i];
          if (MODE >= 1) v = fmaxf(v, 0.f);
          if (MODE == 2) v *= QSCALE;
          C0[rowg * (size_t)N + bn + wn + nt * 16 + l15] = f2bfbits(v);
        }
      }
  }
}

// ---------------------------------------------------------------------------
// Output MFMA GEMM: out[M,N] = A[M,K] @ Bt[N,K]^T + bias[N], fp32 out.
// 128(M) x 64(N) tile, BK=64.  N=1024 too narrow for 256^2 tiles.
// ---------------------------------------------------------------------------
__global__ __launch_bounds__(256) void gemm_out_bf16(
    const unsigned short* __restrict__ A,   // [M][K] bf16
    const unsigned short* __restrict__ Bt,  // [N][K] bf16
    const float* __restrict__ bias,
    float* __restrict__ out, int M, int N, int K)
{
  __shared__ __align__(16) unsigned short As[128 * 64];  // 16 KB
  __shared__ __align__(16) unsigned short Bs[64 * 64];   //  8 KB

  int bxi, byi;
  swizzle_xy(bxi, byi);
  const int tid  = threadIdx.x;
  const int bm   = byi * 128;
  const int bn   = bxi * 64;
  const int lane = tid & 63;
  const int w    = tid >> 6;
  const int wm   = (w & 1) * 64;
  const int wn   = (w >> 1) * 32;
  const int quad = lane >> 4;
  const int l15  = lane & 15;

  f32x4_t acc[4][2];
#pragma unroll
  for (int mt = 0; mt < 4; ++mt)
#pragma unroll
    for (int nt = 0; nt < 2; ++nt) acc[mt][nt] = (f32x4_t){0.f, 0.f, 0.f, 0.f};

  int qa[4], ra[4], ca[4];
#pragma unroll
  for (int j = 0; j < 4; ++j) {
    qa[j] = tid + 256 * j;
    ra[j] = qa[j] >> 3;
    ca[j] = (qa[j] & 7) ^ (ra[j] & 7);
  }
  int qb[2], rb[2], cb[2];
#pragma unroll
  for (int j = 0; j < 2; ++j) {
    qb[j] = tid + 256 * j;
    rb[j] = qb[j] >> 3;
    cb[j] = (qb[j] & 7) ^ (rb[j] & 7);
  }

  for (int k0 = 0; k0 < K; k0 += 64) {
    __syncthreads();
#pragma unroll
    for (int j = 0; j < 4; ++j)
      load_lds16(&A[(size_t)(bm + ra[j]) * K + k0 + ca[j] * 8], &As[qa[j] * 8]);
#pragma unroll
    for (int j = 0; j < 2; ++j)
      load_lds16(&Bt[(size_t)(bn + rb[j]) * K + k0 + cb[j] * 8], &Bs[qb[j] * 8]);
    __syncthreads();

    bf16x8_t af[4][2], bfr[2][2];
#pragma unroll
    for (int mt = 0; mt < 4; ++mt) {
      const int r = wm + mt * 16 + l15;
#pragma unroll
      for (int kt = 0; kt < 2; ++kt) {
        const int slot = (kt * 4 + quad) ^ (r & 7);
        af[mt][kt] = *reinterpret_cast<const bf16x8_t*>(&As[r * 64 + slot * 8]);
      }
    }
#pragma unroll
    for (int nt = 0; nt < 2; ++nt) {
      const int r = wn + nt * 16 + l15;
#pragma unroll
      for (int kt = 0; kt < 2; ++kt) {
        const int slot = (kt * 4 + quad) ^ (r & 7);
        bfr[nt][kt] = *reinterpret_cast<const bf16x8_t*>(&Bs[r * 64 + slot * 8]);
      }
    }
#pragma unroll
    for (int mt = 0; mt < 4; ++mt)
#pragma unroll
      for (int nt = 0; nt < 2; ++nt) {
        acc[mt][nt] = __builtin_amdgcn_mfma_f32_16x16x32_bf16(
            af[mt][0], bfr[nt][0], acc[mt][nt], 0, 0, 0);
        acc[mt][nt] = __builtin_amdgcn_mfma_f32_16x16x32_bf16(
            af[mt][1], bfr[nt][1], acc[mt][nt], 0, 0, 0);
      }
  }

#pragma unroll
  for (int mt = 0; mt < 4; ++mt)
#pragma unroll
    for (int i = 0; i < 4; ++i) {
      const size_t rowg = (size_t)(bm + wm + mt * 16 + quad * 4 + i);
#pragma unroll
      for (int nt = 0; nt < 2; ++nt) {
        const int colg = bn + wn + nt * 16 + l15;
        out[rowg * N + colg] = acc[mt][nt][i] + bias[colg];
      }
    }
}

// ---------------------------------------------------------------------------
// ksum[t][d] = sum_i K[t][i*64+d].  One wave per token, 4 tokens/block.
// ---------------------------------------------------------------------------
__global__ __launch_bounds__(256) void ksum_kernel(
    const unsigned short* __restrict__ Kb, float* __restrict__ ks)
{
  const int t = blockIdx.x * 4 + (threadIdx.x >> 6);
  const int j = threadIdx.x & 63;
  const uint4* row = reinterpret_cast<const uint4*>(Kb + (size_t)t * INNER);
  float s[8] = {0.f, 0.f, 0.f, 0.f, 0.f, 0.f, 0.f, 0.f};
#pragma unroll
  for (int m = 0; m < 8; ++m) {
    const uint4 u = row[j + 64 * m];
    s[0] += __uint_as_float((u.x & 0xFFFFu) << 16);
    s[1] += __uint_as_float(u.x & 0xFFFF0000u);
    s[2] += __uint_as_float((u.y & 0xFFFFu) << 16);
    s[3] += __uint_as_float(u.y & 0xFFFF0000u);
    s[4] += __uint_as_float((u.z & 0xFFFFu) << 16);
    s[5] += __uint_as_float(u.z & 0xFFFF0000u);
    s[6] += __uint_as_float((u.w & 0xFFFFu) << 16);
    s[7] += __uint_as_float(u.w & 0xFFFF0000u);
  }
#pragma unroll
  for (int off = 8; off < 64; off <<= 1)
#pragma unroll
    for (int e = 0; e < 8; ++e) s[e] += __shfl_xor(s[e], off, 64);
  if (j < 8) {
    float4* dst = reinterpret_cast<float4*>(ks + t * 64 + j * 8);
    float4 lo, hi;
    lo.x = s[0]; lo.y = s[1]; lo.z = s[2]; lo.w = s[3];
    hi.x = s[4]; hi.y = s[5]; hi.z = s[6]; hi.w = s[7];
    dst[0] = lo; dst[1] = hi;
  }
}

// ---------------------------------------------------------------------------
// MFMA attention: one wave per token, 4 tokens/block, zero LDS.
// ---------------------------------------------------------------------------
__global__ __launch_bounds__(256) void attn_mfma(
    const unsigned short* __restrict__ Qb, const unsigned short* __restrict__ Vb,
    const float* __restrict__ ksum, unsigned short* __restrict__ Ab)
{
  const int t    = blockIdx.x * 4 + (threadIdx.x >> 6);
  const int lane = threadIdx.x & 63;
  const int l15  = lane & 15;
  const int quad = lane >> 4;
  const size_t base = (size_t)t * INNER;

  union VU { bf16x8_t v; unsigned short u[8]; };

  float ksv[2][8];
#pragma unroll
  for (int kt = 0; kt < 2; ++kt) {
    const float4* p = reinterpret_cast<const float4*>(ksum + t * 64 + kt * 32 + quad * 8);
    const float4 a = p[0], b = p[1];
    ksv[kt][0] = a.x; ksv[kt][1] = a.y; ksv[kt][2] = a.z; ksv[kt][3] = a.w;
    ksv[kt][4] = b.x; ksv[kt][5] = b.y; ksv[kt][6] = b.z; ksv[kt][7] = b.w;
  }

  bf16x8_t vs[4][2];
#pragma unroll
  for (int nt = 0; nt < 4; ++nt)
#pragma unroll
    for (int kt = 0; kt < 2; ++kt) {
      VU vr, vo;
      vr.v = *reinterpret_cast<const bf16x8_t*>(
          Vb + base + (size_t)(nt * 16 + l15) * 64 + kt * 32 + quad * 8);
#pragma unroll
      for (int j = 0; j < 8; ++j)
        vo.u[j] = f2bfbits(bfbits2f(vr.u[j]) * ksv[kt][j]);
      vs[nt][kt] = vo.v;
    }

  bf16x8_t qf[4][2];
  float qn[4] = {0.f, 0.f, 0.f, 0.f};
#pragma unroll
  for (int mt = 0; mt < 4; ++mt)
#pragma unroll
    for (int kt = 0; kt < 2; ++kt) {
      VU qr;
      qr.v = *reinterpret_cast<const bf16x8_t*>(
          Qb + base + (size_t)(mt * 16 + l15) * 64 + kt * 32 + quad * 8);
      qf[mt][kt] = qr.v;
#pragma unroll
      for (int j = 0; j < 8; ++j)
        qn[mt] += bfbits2f(qr.u[j]) * ksv[kt][j];
    }
#pragma unroll
  for (int mt = 0; mt < 4; ++mt) {
    qn[mt] += __shfl_xor(qn[mt], 16, 64);
    qn[mt] += __shfl_xor(qn[mt], 32, 64);
  }

  f32x4_t acc[4][4];
#pragma unroll
  for (int mt = 0; mt < 4; ++mt)
#pragma unroll
    for (int nt = 0; nt < 4; ++nt) acc[mt][nt] = (f32x4_t){0.f, 0.f, 0.f, 0.f};

#pragma unroll
  for (int mt = 0; mt < 4; ++mt)
#pragma unroll
    for (int nt = 0; nt < 4; ++nt) {
      acc[mt][nt] = __builtin_amdgcn_mfma_f32_16x16x32_bf16(
          qf[mt][0], vs[nt][0], acc[mt][nt], 0, 0, 0);
      acc[mt][nt] = __builtin_amdgcn_mfma_f32_16x16x32_bf16(
          qf[mt][1], vs[nt][1], acc[mt][nt], 0, 0, 0);
    }

#pragma unroll
  for (int mt = 0; mt < 4; ++mt)
#pragma unroll
    for (int i = 0; i < 4; ++i) {
      const float inv = 1.f / (__shfl(qn[mt], quad * 4 + i, 64) + EPS);
      const size_t roff = base + (size_t)(mt * 16 + quad * 4 + i) * 64;
#pragma unroll
      for (int nt = 0; nt < 4; ++nt)
        Ab[roff + nt * 16 + l15] = f2bfbits(acc[mt][nt][i] * inv);
    }
}

// ---------------------------------------------------------------------------
// Buffers (ws = 130 MB):
//  ws   @0      : K (transient) -> Q -> A (in place)
//  ws   @64MB   : V ; first 8MB reused for Wo^T after attn
//  ws   @128MB  : ksum (fp32 8192x64, 2MB)
//  d_out@0      : Xb (bf16 8192x1024, 16MB)       — dead before gemm_out writes
//  d_out@16MB   : WtKV (bf16 8192x1024, 16MB)     — then WqT (8MB)
// ---------------------------------------------------------------------------
extern "C" void kernel_launch(void* const* d_in, const int* in_sizes, int n_in,
                              void* d_out, int out_size, void* d_ws, size_t ws_size,
                              hipStream_t stream)
{
  const float* x  = (const float*)d_in[0];
  const float* Wq = (const float*)d_in[1];
  const float* Wk = (const float*)d_in[2];
  const float* Wv = (const float*)d_in[3];
  const float* Wo = (const float*)d_in[4];
  const float* bo = (const float*)d_in[5];
  float* out = (float*)d_out;

  uint8_t* ws = (uint8_t*)d_ws;
  const size_t HALF = (size_t)M_TOK * INNER * sizeof(bf16);  // 64 MB
  unsigned short* KQA = (unsigned short*)ws;            // K -> Q -> A
  unsigned short* Vb  = (unsigned short*)(ws + HALF);   // V ; then Wo^T
  float* ks           = (float*)(ws + 2 * HALF);

  unsigned short* Xb   = (unsigned short*)d_out;                           // 16 MB
  unsigned short* WtKV = (unsigned short*)((uint8_t*)d_out + (16u << 20)); // 16 MB
  unsigned short* WqT  = WtKV;   // reused after gemm_kv
  unsigned short* Wot  = Vb;     // Wo^T over dead V (after attn)

  const dim3 blk(256);
  const dim3 blk512(512);

  castx_kernel<<<dim3(M_TOK * DIM / 4 / 256), blk, 0, stream>>>(
      x, Xb, M_TOK * DIM / 4);

  // Wk^T and Wv^T stacked -> WtKV [8192][1024]
  tcast_dual_kernel<<<dim3(INNER / 32, DIM / 32, 2), blk, 0, stream>>>(
      Wk, Wv, WtKV, DIM, INNER);

  // fused K+V projection: 256^2 slip-pipelined, DUAL epilogue (relu->K, id->V)
  gemm256<0, 1><<<dim3(2 * INNER / 256, M_TOK / 256), blk512, 0, stream>>>(
      Xb, WtKV, KQA, Vb, 2 * INNER, DIM);

  ksum_kernel<<<dim3(M_TOK / 4), blk, 0, stream>>>(KQA, ks);

  tcast_kernel<<<dim3(INNER / 32, DIM / 32), blk, 0, stream>>>(
      Wq, WqT, DIM, INNER);

  // Q projection: relu * QSCALE, overwrites dead K
  gemm256<2, 0><<<dim3(INNER / 256, M_TOK / 256), blk512, 0, stream>>>(
      Xb, WqT, KQA, nullptr, INNER, DIM);

  attn_mfma<<<dim3(M_TOK / 4), blk, 0, stream>>>(KQA, Vb, ks, KQA);  // A in place

  tcast_kernel<<<dim3(DIM / 32, INNER / 32), blk, 0, stream>>>(
      Wo, Wot, INNER, DIM);  // over dead V

  gemm_out_bf16<<<dim3(DIM / 64, M_TOK / 128), blk, 0, stream>>>(
      KQA, Wot, bo, out, M_TOK, DIM, INNER);
}